// Round 7
// baseline (185.651 us; speedup 1.0000x reference)
//
#include <hip/hip_runtime.h>
#include <math.h>

#define THREADS 256
#define CAP 512
#define HIST_BINS 4096
#define RAW_THRESH 2.5f
#define SEGLEN 8192   // floats per sweep segment (32 KB)

typedef float f32x4 __attribute__((ext_vector_type(4)));

__device__ __forceinline__ unsigned orderKey(float f) {
    unsigned u = __float_as_uint(f);
    return (u & 0x80000000u) ? ~u : (u | 0x80000000u);
}

// ws layout, derived identically in every kernel from device-readable nrows.
struct WS {
    int* mark; int* cnt;
    float* gvals; int* gidx;
    float* prob; int* tok;
};
__device__ __forceinline__ WS ws_layout(void* ws, int nrows, int total) {
    WS w;
    w.mark = (int*)ws;
    w.cnt  = w.mark + nrows;
    w.gvals = (float*)(w.cnt + nrows);
    w.gidx  = (int*)(w.gvals + (size_t)nrows * CAP);
    w.prob  = (float*)(w.gidx + (size_t)nrows * CAP);
    w.tok   = (int*)(w.prob + total);
    return w;
}

// Zero mark[] and cnt[].
__global__ void setup_kernel(const int* __restrict__ cuq, int bsz, int total, void* ws) {
    const int nrows = cuq[bsz];
    WS w = ws_layout(ws, nrows, total);
    for (int i = blockIdx.x * blockDim.x + threadIdx.x; i < nrows; i += gridDim.x * blockDim.x) {
        w.mark[i] = 0;
        w.cnt[i] = 0;
    }
}

// One thread per candidate: mark referenced rows.
__global__ void mark_kernel(const int* __restrict__ rel_idx,
                            const int* __restrict__ cuf,
                            const int* __restrict__ cuq,
                            int bsz, int total, void* ws) {
    const int t = blockIdx.x * blockDim.x + threadIdx.x;
    if (t >= total) return;
    const int nrows = cuq[bsz];
    WS w = ws_layout(ws, nrows, total);
    int lo = 0, hi = bsz;
    while (hi - lo > 1) { int mid = (lo + hi) >> 1; if (t >= cuf[mid]) lo = mid; else hi = mid; }
    w.mark[cuq[lo] + rel_idx[t]] = 1;
}

#define GC1(x, gi) \
    if ((x) >= RAW_THRESH) { \
        int p = atomicAdd(&w.cnt[row], 1); \
        if (p < CAP) { w.gvals[(size_t)row * CAP + p] = (x); w.gidx[(size_t)row * CAP + p] = (gi); } \
    }
#define GC4(vv, base) \
    GC1((vv).x, (base)) GC1((vv).y, (base) + 1) \
    GC1((vv).z, (base) + 2) GC1((vv).w, (base) + 3)

// Address-ordered sweep over 32KB segments of NEEDED rows (mark-skip).
// Collect raw >= RAW_THRESH into per-row global arrays.
__global__ __launch_bounds__(THREADS, 8) void sweep_kernel(
    const float* __restrict__ logits,
    const int* __restrict__ cuq,
    int bsz, int total, long long logits_n, void* ws)
{
    const int tid = threadIdx.x;
    const int nrows = cuq[bsz];
    const int vocab = (int)(logits_n / (long long)nrows);
    WS w = ws_layout(ws, nrows, total);

    const int segs_per_row = (vocab + SEGLEN - 1) / SEGLEN;
    const long long totsegs = (long long)nrows * segs_per_row;

    for (long long s = blockIdx.x; s < totsegs; s += gridDim.x) {
        const int row = (int)(s / segs_per_row);
        if (!w.mark[row]) continue;
        const int s0 = (int)(s % segs_per_row) * SEGLEN;
        const int s1 = (s0 + SEGLEN < vocab) ? s0 + SEGLEN : vocab;
        const float* rp = logits + (long long)row * (long long)vocab;
        const f32x4* rp4 = (const f32x4*)rp;
        const int c4beg = s0 >> 2, c4end = s1 >> 2;

        int i = c4beg + tid;
        for (; i + THREADS < c4end; i += 2 * THREADS) {
            f32x4 a = rp4[i];
            f32x4 b = rp4[i + THREADS];
            GC4(a, i << 2)
            GC4(b, (i + THREADS) << 2)
        }
        for (; i < c4end; i += THREADS) {
            f32x4 a = rp4[i];
            GC4(a, i << 2)
        }
        for (int j = (c4end << 2) + tid; j < s1; j += THREADS) {
            float x = rp[j];
            GC1(x, j)
        }
    }
}

// One wave per candidate token: sort its row's collected (raw,idx) set, scale
// by this token's temperature, then the exact top-k / top-p / softmax epilogue.
// Full-row histogram fallback if collection under/overflowed (never on data).
__global__ __launch_bounds__(64) void token_kernel(
    const float* __restrict__ logits,
    const int* __restrict__ rel_idx,
    const int* __restrict__ cuf,
    const int* __restrict__ cuq,
    const float* __restrict__ temps,
    const int* __restrict__ topk_p,
    const float* __restrict__ topp_p,
    int bsz, int total, long long logits_n, void* ws)
{
    __shared__ union {
        struct { float sc[CAP]; int si[CAP]; float sv[CAP]; float e[CAP]; } a;  // 8 KB
        int hist[HIST_BINS];                                                    // 16 KB
    } u;
    __shared__ int s_m, s_amax, s_n;
    __shared__ unsigned s_T, s_maxkey;

    const int t = blockIdx.x;
    const int l = threadIdx.x;
    const int nrows = cuq[bsz];
    const int vocab = (int)(logits_n / (long long)nrows);
    int kk = topk_p[0];
    if (kk > vocab) kk = vocab;

    WS w = ws_layout(ws, nrows, total);

    int lo = 0, hi = bsz;
    while (hi - lo > 1) { int mid = (lo + hi) >> 1; if (t >= cuf[mid]) lo = mid; else hi = mid; }
    const int row = cuq[lo] + rel_idx[t];
    const float T = temps[t];
    const float* rp = logits + (long long)row * (long long)vocab;
    int n = w.cnt[row];

    if (n >= kk && n <= CAP) {
        // main path: load collected (raw, idx), scale by T
        for (int j = l; j < n; j += 64) {
            u.a.sc[j] = w.gvals[(size_t)row * CAP + j] / T;
            u.a.si[j] = w.gidx[(size_t)row * CAP + j];
        }
    } else {
        // ---- fallback: exact raw-space histogram over the full row ----
        for (int j = l; j < HIST_BINS; j += 64) u.hist[j] = 0;
        if (l == 0) { s_n = 0; s_maxkey = 0; }
        __syncthreads();
        for (int j = l; j < vocab; j += 64) {
            unsigned k = orderKey(rp[j]);
            atomicAdd(&u.hist[k >> 20], 1);
            atomicMax(&s_maxkey, k);
        }
        __syncthreads();
        if (l == 0) {
            int B = (int)(s_maxkey >> 20);
            int cum = 0;
            while (true) {
                cum += u.hist[B];
                if (cum >= kk || B == 0) break;
                --B;
            }
            s_T = ((unsigned)B) << 20;
        }
        __syncthreads();
        const unsigned Tk = s_T;
        __syncthreads();   // hist reads done before union reuse
        for (int j = l; j < vocab; j += 64) {
            float a = rp[j];
            if (orderKey(a) >= Tk) {
                int p = atomicAdd(&s_n, 1);
                if (p < CAP) { u.a.sc[p] = a / T; u.a.si[p] = j; }
            }
        }
        __syncthreads();
        n = s_n;
        if (n > CAP) n = CAP;
        if (kk > n) kk = n;
    }
    __syncthreads();

    // ---- rank-sort scaled values (desc, original index asc) ----
    for (int j = l; j < n; j += 64) {
        float v = u.a.sc[j];
        int id = u.a.si[j];
        int r = 0;
        for (int q = 0; q < n; ++q) {
            float x = u.a.sc[q];
            r += (x > v) || (x == v && u.a.si[q] < id);
        }
        u.a.sv[r] = v;
    }
    __syncthreads();
    const float M = u.a.sv[0];
    const float thrk = u.a.sv[kk - 1];

    int mcnt = 0;
    int cand = 0x7fffffff;
    for (int j = l; j < n; j += 64) {
        mcnt += (u.a.sc[j] >= thrk) ? 1 : 0;
        if (u.a.sc[j] == M && u.a.si[j] < cand) cand = u.a.si[j];
    }
    for (int off = 32; off > 0; off >>= 1) {
        mcnt += __shfl_down(mcnt, off);
        int oc = __shfl_down(cand, off);
        if (oc < cand) cand = oc;
    }
    if (l == 0) { s_m = mcnt; s_amax = cand; }
    __syncthreads();
    const int m = s_m;
    for (int j = l; j < m; j += 64) u.a.e[j] = expf(u.a.sv[j] - M);
    __syncthreads();
    if (l == 0) {
        float Z1 = 0.f;
        for (int j = 0; j < m; ++j) Z1 += u.a.e[j];
        const float topp = topp_p[0];
        int jcut = m - 1;
        float c = 0.f;
        for (int j = 0; j < m; ++j) {
            float p = u.a.e[j] / Z1;
            c += p;
            if (c > topp) { jcut = j; break; }
        }
        float Z2 = 0.f;
        for (int j = 0; j <= jcut; ++j) Z2 += u.a.e[j];
        w.prob[t] = 1.0f / Z2;
        w.tok[t] = s_amax;
    }
}

// One wave per batch: stable sort by score desc, filter, write int32 outputs.
__global__ __launch_bounds__(64) void finalize_kernel(
    const int* __restrict__ rel_idx,
    const int* __restrict__ boff,
    const int* __restrict__ cuf,
    const int* __restrict__ cuq,
    const int* __restrict__ num_transfer,
    const float* __restrict__ thresholds,
    int bsz, int total, int L,
    void* ws,
    int* __restrict__ out)
{
    const int bq = blockIdx.x;
    const int l = threadIdx.x;
    const int nrows = cuq[bsz];
    WS w = ws_layout(ws, nrows, total);

    const int start = cuf[bq];
    int cnt = cuf[bq + 1] - start;
    if (cnt > L) cnt = L;

    __shared__ float ss[64]; __shared__ int stk[64]; __shared__ int sp[64];
    __shared__ float ss2[64]; __shared__ int stk2[64]; __shared__ int sp2[64];

    float score = -INFINITY; int tk = 0; int pos = 0;
    if (l < L) {
        if (l < cnt) {
            int t = start + l;
            score = w.prob[t];
            tk = w.tok[t];
            pos = rel_idx[t] + boff[bq];
        }
        ss[l] = score; stk[l] = tk; sp[l] = pos;
    }
    __syncthreads();
    if (l < L) {
        int r = 0;
        for (int j = 0; j < L; ++j) {
            float x = ss[j];
            r += (x > score) || (x == score && j < l);
        }
        ss2[r] = score; stk2[r] = tk; sp2[r] = pos;
    }
    __syncthreads();

    int k = num_transfer[bq]; if (k < 0) k = 0;
    const float thrb = thresholds[bq];
    bool kp = false;
    if (l < L) {
        float s = ss2[l];
        kp = (l < k) && (s >= thrb) && (s > -INFINITY);
        out[bq * L + l] = kp ? sp2[l] : 0;
        out[bsz * L + bq * L + l] = kp ? stk2[l] : -1;
    }
    unsigned long long mask = __ballot(kp);
    if (l == 0) out[2 * bsz * L + bq] = (int)__popcll(mask);
}

extern "C" void kernel_launch(void* const* d_in, const int* in_sizes, int n_in,
                              void* d_out, int out_size, void* d_ws, size_t ws_size,
                              hipStream_t stream) {
    const float* logits   = (const float*)d_in[0];
    const int*   rel      = (const int*)d_in[1];
    const int*   boff     = (const int*)d_in[2];
    const int*   cuf      = (const int*)d_in[3];
    const int*   cuq      = (const int*)d_in[4];
    const float* temps    = (const float*)d_in[5];
    const int*   ntr      = (const int*)d_in[6];
    const float* thr      = (const float*)d_in[7];
    const float* topp     = (const float*)d_in[8];
    const int*   topk     = (const int*)d_in[9];

    const int total = in_sizes[1];
    const int bsz   = in_sizes[6];
    const long long logits_n = (long long)in_sizes[0];
    const int L = (out_size - bsz) / (2 * bsz);   // block_size

    setup_kernel<<<32, 256, 0, stream>>>(cuq, bsz, total, d_ws);

    mark_kernel<<<(total + 255) / 256, 256, 0, stream>>>(
        rel, cuf, cuq, bsz, total, d_ws);

    sweep_kernel<<<2048, THREADS, 0, stream>>>(
        logits, cuq, bsz, total, logits_n, d_ws);

    token_kernel<<<total, 64, 0, stream>>>(
        logits, rel, cuf, cuq, temps, topk, topp, bsz, total, logits_n, d_ws);

    finalize_kernel<<<bsz, 64, 0, stream>>>(
        rel, boff, cuf, cuq, ntr, thr, bsz, total, L, d_ws, (int*)d_out);
}

// Round 8
// 80.735 us; speedup vs baseline: 2.2995x; 2.2995x over previous
//
#include <hip/hip_runtime.h>
#include <math.h>

#define THREADS 256
#define CAP 512
#define HIST_BINS 4096
#define RAW_THRESH 2.5f

typedef float f32x4 __attribute__((ext_vector_type(4)));

__device__ __forceinline__ unsigned orderKey(float f) {
    unsigned u = __float_as_uint(f);
    return (u & 0x80000000u) ? ~u : (u | 0x80000000u);
}

// ws layout, derived identically in every kernel from device-readable nrows.
struct WS {
    float* svals; int* sidx; int* wsn;
    float* prob; int* tok;
};
__device__ __forceinline__ WS ws_layout(void* ws, int nrows, int total) {
    WS w;
    w.svals = (float*)ws;
    w.sidx  = (int*)(w.svals + (size_t)nrows * CAP);
    w.wsn   = w.sidx + (size_t)nrows * CAP;
    w.prob  = (float*)(w.wsn + nrows);
    w.tok   = (int*)(w.prob + total);
    return w;
}

#define COLLECT1(x, gi) \
    if ((x) >= RAW_THRESH) { int p = atomicAdd(&s_n, 1); if (p < CAP) { u.a.v[p] = (x); u.a.id[p] = (gi); } }
#define COLLECT4(vv, base) \
    COLLECT1((vv).x, (base)) COLLECT1((vv).y, (base) + 1) \
    COLLECT1((vv).z, (base) + 2) COLLECT1((vv).w, (base) + 3)

// Grid-stride over rows (block ~ one row). Skip rows not referenced by any
// candidate of their batch (self-check; no extra kernels). Single streaming
// pass collecting raw >= RAW_THRESH into LDS (superset of top-kk whenever
// count >= kk; exact raw-space histogram fallback otherwise), LDS rank-sort
// descending (idx-asc ties), write sorted (val,idx)+count to ws.
__global__ __launch_bounds__(THREADS, 8) void row_kernel(
    const float* __restrict__ logits,
    const int* __restrict__ rel_idx,
    const int* __restrict__ cuf,
    const int* __restrict__ cuq,
    const int* __restrict__ topk_p,
    int bsz, int total, long long logits_n, void* ws)
{
    __shared__ union {
        struct { float v[CAP]; int id[CAP]; float sv[CAP]; int si[CAP]; } a;  // 8 KB
        int hist[HIST_BINS];                                                  // 16 KB
    } u;
    __shared__ int s_n, s_needed;
    __shared__ unsigned s_T, s_maxkey;

    const int tid = threadIdx.x;
    const int nrows = cuq[bsz];
    const int vocab = (int)(logits_n / (long long)nrows);
    int kk = topk_p[0];
    if (kk > vocab) kk = vocab;

    WS w = ws_layout(ws, nrows, total);

    for (int r = blockIdx.x; r < nrows; r += gridDim.x) {
        // batch owning this row
        int lo = 0, hi = bsz;
        while (hi - lo > 1) { int mid = (lo + hi) >> 1; if (r >= cuq[mid]) lo = mid; else hi = mid; }
        const int b = lo;
        const int rel = r - cuq[b];

        if (tid == 0) { s_needed = 0; s_n = 0; }
        __syncthreads();
        const int t0 = cuf[b], cnt = cuf[b + 1] - t0;
        for (int l = tid; l < cnt; l += THREADS)
            if (rel_idx[t0 + l] == rel) s_needed = 1;
        __syncthreads();
        if (!s_needed) continue;

        const float* rp = logits + (long long)r * (long long)vocab;
        const f32x4* rp4 = (const f32x4*)rp;
        const int nv4 = vocab >> 2;

        // ---- single streaming pass: 2 float4/thread/iter, fmax-tree guard ----
        int i = tid;
        for (; i + THREADS < nv4; i += 2 * THREADS) {
            f32x4 a = rp4[i];
            f32x4 c = rp4[i + THREADS];
            float mx = fmaxf(fmaxf(fmaxf(a.x, a.y), fmaxf(a.z, a.w)),
                             fmaxf(fmaxf(c.x, c.y), fmaxf(c.z, c.w)));
            if (mx >= RAW_THRESH) {
                COLLECT4(a, i << 2)
                COLLECT4(c, (i + THREADS) << 2)
            }
        }
        for (; i < nv4; i += THREADS) {
            f32x4 a = rp4[i];
            float mx = fmaxf(fmaxf(a.x, a.y), fmaxf(a.z, a.w));
            if (mx >= RAW_THRESH) {
                COLLECT4(a, i << 2)
            }
        }
        for (int j = (nv4 << 2) + tid; j < vocab; j += THREADS) {
            float x = rp[j];
            COLLECT1(x, j)
        }
        __syncthreads();
        int n = s_n;

        if (n < kk || n > CAP) {
            // ---- fallback: exact raw-space histogram threshold ----
            __syncthreads();
            for (int j = tid; j < HIST_BINS; j += THREADS) u.hist[j] = 0;
            if (tid == 0) { s_n = 0; s_maxkey = 0; }
            __syncthreads();
            for (int j = tid; j < vocab; j += THREADS) {
                unsigned k = orderKey(rp[j]);
                atomicAdd(&u.hist[k >> 20], 1);
                atomicMax(&s_maxkey, k);
            }
            __syncthreads();
            if (tid == 0) {
                int B = (int)(s_maxkey >> 20);
                int cum = 0;
                while (true) {
                    cum += u.hist[B];
                    if (cum >= kk || B == 0) break;
                    --B;
                }
                s_T = ((unsigned)B) << 20;
            }
            __syncthreads();
            const unsigned Tk = s_T;
            __syncthreads();
            for (int j = tid; j < vocab; j += THREADS) {
                float a = rp[j];
                if (orderKey(a) >= Tk) {
                    int p = atomicAdd(&s_n, 1);
                    if (p < CAP) { u.a.v[p] = a; u.a.id[p] = j; }
                }
            }
            __syncthreads();
            n = s_n;
            if (n > CAP) n = CAP;
        }

        // ---- rank-sort (value desc, original index asc) ----
        for (int j = tid; j < n; j += THREADS) {
            float v = u.a.v[j];
            int id = u.a.id[j];
            int rk = 0;
            for (int q = 0; q < n; ++q) {
                float x = u.a.v[q];
                rk += (x > v) || (x == v && u.a.id[q] < id);
            }
            u.a.sv[rk] = v;
            u.a.si[rk] = id;
        }
        __syncthreads();
        for (int j = tid; j < n; j += THREADS) {
            w.svals[(size_t)r * CAP + j] = u.a.sv[j];
            w.sidx[(size_t)r * CAP + j]  = u.a.si[j];
        }
        if (tid == 0) w.wsn[r] = n;
        __syncthreads();   // LDS reused if another grid-stride iteration
    }
}

// One wave per candidate token: load the row's sorted raws (order preserved
// under /T), scale, top-k tie count, first-index argmax, exact sequential
// softmax / cumsum / top-p epilogue. Full-row histogram fallback kept.
__global__ __launch_bounds__(64) void token_kernel(
    const float* __restrict__ logits,
    const int* __restrict__ rel_idx,
    const int* __restrict__ cuf,
    const int* __restrict__ cuq,
    const float* __restrict__ temps,
    const int* __restrict__ topk_p,
    const float* __restrict__ topp_p,
    int bsz, int total, long long logits_n, void* ws)
{
    __shared__ union {
        struct { float sv[CAP]; int si[CAP]; float e[CAP]; } a;  // 6 KB
        int hist[HIST_BINS];                                     // 16 KB
    } u;
    __shared__ int s_m, s_amax, s_n;
    __shared__ unsigned s_T, s_maxkey;

    const int t = blockIdx.x;
    const int l = threadIdx.x;
    const int nrows = cuq[bsz];
    const int vocab = (int)(logits_n / (long long)nrows);
    int kk = topk_p[0];
    if (kk > vocab) kk = vocab;

    WS w = ws_layout(ws, nrows, total);

    int lo = 0, hi = bsz;
    while (hi - lo > 1) { int mid = (lo + hi) >> 1; if (t >= cuf[mid]) lo = mid; else hi = mid; }
    const int row = cuq[lo] + rel_idx[t];
    const float T = temps[t];
    const float* rp = logits + (long long)row * (long long)vocab;
    int n = w.wsn[row];

    if (n >= kk && n <= CAP) {
        // main path: already sorted by raw desc (idx-asc ties); /T preserves order
        for (int j = l; j < n; j += 64) {
            u.a.sv[j] = w.svals[(size_t)row * CAP + j] / T;
            u.a.si[j] = w.sidx[(size_t)row * CAP + j];
        }
        __syncthreads();
    } else {
        // ---- fallback: exact raw-space histogram over the full row ----
        for (int j = l; j < HIST_BINS; j += 64) u.hist[j] = 0;
        if (l == 0) { s_n = 0; s_maxkey = 0; }
        __syncthreads();
        for (int j = l; j < vocab; j += 64) {
            unsigned k = orderKey(rp[j]);
            atomicAdd(&u.hist[k >> 20], 1);
            atomicMax(&s_maxkey, k);
        }
        __syncthreads();
        if (l == 0) {
            int B = (int)(s_maxkey >> 20);
            int cum = 0;
            while (true) {
                cum += u.hist[B];
                if (cum >= kk || B == 0) break;
                --B;
            }
            s_T = ((unsigned)B) << 20;
        }
        __syncthreads();
        const unsigned Tk = s_T;
        __syncthreads();   // hist reads done before union reuse
        for (int j = l; j < vocab; j += 64) {
            float a = rp[j];
            if (orderKey(a) >= Tk) {
                int p = atomicAdd(&s_n, 1);
                if (p < CAP) { u.a.sv[p] = a / T; u.a.si[p] = j; }
            }
        }
        __syncthreads();
        n = s_n;
        if (n > CAP) n = CAP;
        if (kk > n) kk = n;
        // rank-sort (desc, idx-asc) in-place via registers then rewrite
        float v = 0.f; int id = 0; int rk = -1;
        for (int j = l; j < n; j += 64) {
            v = u.a.sv[j]; id = u.a.si[j];
            int r2 = 0;
            for (int q = 0; q < n; ++q) {
                float x = u.a.sv[q];
                r2 += (x > v) || (x == v && u.a.si[q] < id);
            }
            rk = r2;
            // store deferred: need all reads done first
            break;   // each lane handles at most ceil(n/64) — handle below
        }
        // general multi-element handling (n can exceed 64)
        float vs[CAP / 64]; int ids[CAP / 64]; int rks[CAP / 64]; int cnt2 = 0;
        for (int j = l; j < n; j += 64) {
            float vv = u.a.sv[j]; int ii = u.a.si[j];
            int r2 = 0;
            for (int q = 0; q < n; ++q) {
                float x = u.a.sv[q];
                r2 += (x > vv) || (x == vv && u.a.si[q] < ii);
            }
            vs[cnt2] = vv; ids[cnt2] = ii; rks[cnt2] = r2; ++cnt2;
        }
        __syncthreads();
        for (int j2 = 0; j2 < cnt2; ++j2) { u.a.sv[rks[j2]] = vs[j2]; u.a.si[rks[j2]] = ids[j2]; }
        __syncthreads();
        (void)v; (void)id; (void)rk;
    }

    const float M = u.a.sv[0];
    const float thrk = u.a.sv[kk - 1];

    int mcnt = 0;
    int cand = 0x7fffffff;
    for (int j = l; j < n; j += 64) {
        mcnt += (u.a.sv[j] >= thrk) ? 1 : 0;
        if (u.a.sv[j] == M && u.a.si[j] < cand) cand = u.a.si[j];
    }
    for (int off = 32; off > 0; off >>= 1) {
        mcnt += __shfl_down(mcnt, off);
        int oc = __shfl_down(cand, off);
        if (oc < cand) cand = oc;
    }
    if (l == 0) { s_m = mcnt; s_amax = cand; }
    __syncthreads();
    const int m = s_m;
    for (int j = l; j < m; j += 64) u.a.e[j] = expf(u.a.sv[j] - M);
    __syncthreads();
    if (l == 0) {
        float Z1 = 0.f;
        for (int j = 0; j < m; ++j) Z1 += u.a.e[j];
        const float topp = topp_p[0];
        int jcut = m - 1;
        float c = 0.f;
        for (int j = 0; j < m; ++j) {
            float p = u.a.e[j] / Z1;
            c += p;
            if (c > topp) { jcut = j; break; }
        }
        float Z2 = 0.f;
        for (int j = 0; j <= jcut; ++j) Z2 += u.a.e[j];
        w.prob[t] = 1.0f / Z2;
        w.tok[t] = s_amax;
    }
}

// One wave per batch: stable sort by score desc, filter, write int32 outputs.
__global__ __launch_bounds__(64) void finalize_kernel(
    const int* __restrict__ rel_idx,
    const int* __restrict__ boff,
    const int* __restrict__ cuf,
    const int* __restrict__ cuq,
    const int* __restrict__ num_transfer,
    const float* __restrict__ thresholds,
    int bsz, int total, int L,
    void* ws,
    int* __restrict__ out)
{
    const int bq = blockIdx.x;
    const int l = threadIdx.x;
    const int nrows = cuq[bsz];
    WS w = ws_layout(ws, nrows, total);

    const int start = cuf[bq];
    int cnt = cuf[bq + 1] - start;
    if (cnt > L) cnt = L;

    __shared__ float ss[64]; __shared__ int stk[64]; __shared__ int sp[64];
    __shared__ float ss2[64]; __shared__ int stk2[64]; __shared__ int sp2[64];

    float score = -INFINITY; int tk = 0; int pos = 0;
    if (l < L) {
        if (l < cnt) {
            int t = start + l;
            score = w.prob[t];
            tk = w.tok[t];
            pos = rel_idx[t] + boff[bq];
        }
        ss[l] = score; stk[l] = tk; sp[l] = pos;
    }
    __syncthreads();
    if (l < L) {
        int r = 0;
        for (int j = 0; j < L; ++j) {
            float x = ss[j];
            r += (x > score) || (x == score && j < l);
        }
        ss2[r] = score; stk2[r] = tk; sp2[r] = pos;
    }
    __syncthreads();

    int k = num_transfer[bq]; if (k < 0) k = 0;
    const float thrb = thresholds[bq];
    bool kp = false;
    if (l < L) {
        float s = ss2[l];
        kp = (l < k) && (s >= thrb) && (s > -INFINITY);
        out[bq * L + l] = kp ? sp2[l] : 0;
        out[bsz * L + bq * L + l] = kp ? stk2[l] : -1;
    }
    unsigned long long mask = __ballot(kp);
    if (l == 0) out[2 * bsz * L + bq] = (int)__popcll(mask);
}

extern "C" void kernel_launch(void* const* d_in, const int* in_sizes, int n_in,
                              void* d_out, int out_size, void* d_ws, size_t ws_size,
                              hipStream_t stream) {
    const float* logits   = (const float*)d_in[0];
    const int*   rel      = (const int*)d_in[1];
    const int*   boff     = (const int*)d_in[2];
    const int*   cuf      = (const int*)d_in[3];
    const int*   cuq      = (const int*)d_in[4];
    const float* temps    = (const float*)d_in[5];
    const int*   ntr      = (const int*)d_in[6];
    const float* thr      = (const float*)d_in[7];
    const float* topp     = (const float*)d_in[8];
    const int*   topk     = (const int*)d_in[9];

    const int total = in_sizes[1];
    const int bsz   = in_sizes[6];
    const long long logits_n = (long long)in_sizes[0];
    const int L = (out_size - bsz) / (2 * bsz);   // block_size

    row_kernel<<<2 * total, THREADS, 0, stream>>>(
        logits, rel, cuf, cuq, topk, bsz, total, logits_n, d_ws);

    token_kernel<<<total, 64, 0, stream>>>(
        logits, rel, cuf, cuq, temps, topk, topp, bsz, total, logits_n, d_ws);

    finalize_kernel<<<bsz, 64, 0, stream>>>(
        rel, boff, cuf, cuq, ntr, thr, bsz, total, L, d_ws, (int*)d_out);
}